// Round 5
// baseline (129.529 us; speedup 1.0000x reference)
//
#include <hip/hip_runtime.h>

// GCN aggregator: out[r,:] = relu( (1/25 * sum_s F[idx[r,s],:]) @ W )
// r in [0, 32768), D_IN = D_OUT = 128, S = 25.
//
// Round 8: concurrency for the phased gather.
//  r7 post-mortem: dur_us decomposes as ~83 us fixed harness ws-poison fills
//  + gemm ~15.5 us + gather ~30 us. Gather floor is ~6 us L2 BW + ~5 us VALU
//  => it is LATENCY-bound: 5-load serialized batches (VGPR=32, no pipeline)
//  at 4 blocks/CU (LDS 38.4 KB) can't hide ~200cy L2 hits.
//  This round: (1) LDS 38.4 -> 10.9 KB (GRB=32, ushort locals, 1 row/thread)
//  -> 6-8 blocks/CU; (2) hand-written two-stage pipeline, batch 4 (load next
//  4 G-rows while accumulating current 4) -> steady-state MLP 8/thread.
//  Index lists padded to a multiple of 4 (min 4) with the slice's zero row,
//  so the inner loop is unconditional and m=0 rows read zeros, not garbage.

#define DEG 25
#define DIM 128
#define NPP 25000          // nodes per range slice (100000 / 4)
#define NPP1 25001         // slice row stride: +1 all-zero pad row

typedef __attribute__((ext_vector_type(8))) short short8;        // 8 bf16
typedef __attribute__((ext_vector_type(4))) float floatx4;       // 4 fp32
typedef __attribute__((ext_vector_type(4))) unsigned int uintx4; // 16 B

__device__ __forceinline__ unsigned short f2bf(float f) {
    // round-to-nearest-even fp32 -> bf16 (inputs finite)
    unsigned u = __float_as_uint(f);
    return (unsigned short)((u + 0x7fffu + ((u >> 16) & 1u)) >> 16);
}

// ---------------------------------------------------------------- GEMM ------
// G[p*2+h][local][64] = bf16( A[node,:] @ B[:, h*64..h*64+63] ),
// node = p*NPP + local. 128-row blocks, 4 waves, 32 rows/wave via MFMA.
#define BSTRIDE 136

__global__ __launch_bounds__(256, 2) void gemm_fw(
    const float* __restrict__ A,       // [M,128] fp32
    const float* __restrict__ B,       // [128,128] fp32
    unsigned short* __restrict__ G,    // [8][NPP1][64] bf16
    int M)
{
    __shared__ unsigned short sBt[DIM * BSTRIDE];  // B^T [n][k], 34.8 KB

    const int tid = threadIdx.x;

    // ---- stage B transposed with fp32->bf16 (once per block)
    {
        const float4* B4 = (const float4*)B;
#pragma unroll
        for (int i = 0; i < 16; ++i) {
            const int linear = i * 256 + tid;   // 0..4095 float4s
            const int k  = linear >> 5;         // B row
            const int c4 = linear & 31;         // float4 within row
            const float4 v = B4[linear];
            const int n = c4 * 4;
            sBt[(n + 0) * BSTRIDE + k] = f2bf(v.x);
            sBt[(n + 1) * BSTRIDE + k] = f2bf(v.y);
            sBt[(n + 2) * BSTRIDE + k] = f2bf(v.z);
            sBt[(n + 3) * BSTRIDE + k] = f2bf(v.w);
        }
    }
    __syncthreads();

    const int wave = tid >> 6;
    const int lane = tid & 63;
    const int quad = lane >> 4;    // 0..3
    const int l16  = lane & 15;

    const int rw0 = blockIdx.x * 128 + wave * 32;   // wave's first row

    floatx4 acc[2][8];
#pragma unroll
    for (int mt = 0; mt < 2; ++mt)
#pragma unroll
        for (int nt = 0; nt < 8; ++nt)
            acc[mt][nt] = (floatx4){0.f, 0.f, 0.f, 0.f};

#pragma unroll
    for (int kt = 0; kt < 4; ++kt) {
        const int k0 = kt * 32;

        // A-frags: lane holds A[m=l16][k=k0+quad*8+j], j=0..7.
        short8 afrag[2];
#pragma unroll
        for (int mt = 0; mt < 2; ++mt) {
            int row = rw0 + mt * 16 + l16;
            if (row >= M) row = M - 1;          // tail clamp (stores guarded)
            const float* ap = A + (size_t)row * DIM + k0 + quad * 8;
            const float4 x = *(const float4*)ap;
            const float4 y = *(const float4*)(ap + 4);
            unsigned p0 = (unsigned)f2bf(x.x) | ((unsigned)f2bf(x.y) << 16);
            unsigned p1 = (unsigned)f2bf(x.z) | ((unsigned)f2bf(x.w) << 16);
            unsigned p2 = (unsigned)f2bf(y.x) | ((unsigned)f2bf(y.y) << 16);
            unsigned p3 = (unsigned)f2bf(y.z) | ((unsigned)f2bf(y.w) << 16);
            uintx4 packed = (uintx4){p0, p1, p2, p3};
            afrag[mt] = __builtin_bit_cast(short8, packed);
        }

        // B-frags from LDS: lane holds B[k=k0+quad*8+j][n=nt*16+l16]
#pragma unroll
        for (int nt = 0; nt < 8; ++nt) {
            const uintx4 u = *(const uintx4*)&sBt[(nt * 16 + l16) * BSTRIDE + k0 + quad * 8];
            const short8 bfrag = __builtin_bit_cast(short8, u);
#pragma unroll
            for (int mt = 0; mt < 2; ++mt)
                acc[mt][nt] = __builtin_amdgcn_mfma_f32_16x16x32_bf16(
                    afrag[mt], bfrag, acc[mt][nt], 0, 0, 0);
        }
    }

    // ---- transpose C tile through LDS (reuse sBt; all B reads are done).
    // C/D frag: elem r of lane = (row 16mt+quad*4+r, col 16nt+l16).
    __syncthreads();   // everyone finished reading sBt
    {
        unsigned short* sT = sBt + wave * (32 * BSTRIDE);
#pragma unroll
        for (int mt = 0; mt < 2; ++mt)
#pragma unroll
            for (int nt = 0; nt < 8; ++nt)
#pragma unroll
                for (int r = 0; r < 4; ++r)
                    sT[(mt * 16 + quad * 4 + r) * BSTRIDE + nt * 16 + l16] =
                        f2bf(acc[mt][nt][r]);
    }
    __syncthreads();   // ordering of LDS writes vs cross-lane reads
    {
        const unsigned short* sT = sBt + wave * (32 * BSTRIDE);
        const int oct   = lane & 7;     // 16 B sub-chunk of the 128 B row
        const int nrow8 = lane >> 3;    // 0..7
        uintx4* G4 = (uintx4*)G;
#pragma unroll
        for (int g = 0; g < 4; ++g) {
            const int lrow = g * 8 + nrow8;
            const int node = rw0 + lrow;
            if (node < M) {
                const unsigned p     = (unsigned)node / NPP;     // const div
                const unsigned local = (unsigned)node - p * NPP;
#pragma unroll
                for (int h = 0; h < 2; ++h) {
                    // 8 octs x 8 nodes => 1 KB contiguous per store instr
                    const uintx4 u = *(const uintx4*)
                        &sT[lrow * BSTRIDE + h * 64 + oct * 8];
                    __builtin_nontemporal_store(u,
                        &G4[((size_t)(p * 2 + h) * NPP1 + local) * 8 + oct]);
                }
            }
        }
        // all-zero pad row (one per slice), used by the gather's padding
        if (blockIdx.x == 0 && tid < 64) {
            const int sl = tid >> 3, o = tid & 7;
            __builtin_nontemporal_store((uintx4){0, 0, 0, 0},
                &G4[((size_t)sl * NPP1 + NPP) * 8 + o]);
        }
    }
}

// -------------------------------------------------- phased gather-mean-relu -
// out[r][h*64 + 0..63] = relu( 1/25 * sum_p sum_{s: idx in range p}
//                               G[p*2+h][idx - p*NPP][0..63] )
// h = blockIdx&1 (spatial: XCD parity); p swept in phases by ALL blocks in
// the same order -> per-phase L2 working set = one 3.2 MB slice per XCD.
// One row per thread (32 rows x 8 octs = 256). Two-stage batch-4 pipeline.
#define GRB 32

__global__ __launch_bounds__(256, 6) void gather_phased(
    const unsigned short* __restrict__ G,   // [8][NPP1][64] bf16
    const int* __restrict__ idx,            // [n_rows,25]
    float* __restrict__ out,                // [n_rows,128] fp32
    int n_rows)
{
    __shared__ int sRaw[GRB * DEG];             // 3.2 KB
    __shared__ unsigned short sC[GRB][4][28];   // 7.0 KB (max m = 28)
    __shared__ int sCnt[GRB][4];                // 0.5 KB

    const int tid  = threadIdx.x;
    const int h    = blockIdx.x & 1;        // col-half == XCD parity
    const int rb   = blockIdx.x >> 1;
    const int row0 = rb * GRB;

    const int* ib = idx + (size_t)row0 * DEG;
    for (int i = tid; i < GRB * DEG; i += 256)
        sRaw[i] = __builtin_nontemporal_load(ib + i);
    __syncthreads();

    // compaction: one thread per (row, range); locals stored as ushort.
    if (tid < GRB * 4) {
        const int row = tid >> 2;
        const int rg  = tid & 3;
        const int lo  = rg * NPP;
        unsigned short* dst = &sC[row][rg][0];
        int cnt = 0;
#pragma unroll
        for (int s = 0; s < DEG; ++s) {
            const unsigned d = (unsigned)(sRaw[row * DEG + s] - lo);
            if (d < NPP) dst[cnt++] = (unsigned short)d;
        }
        int m = ((cnt + 3) / 4) * 4;        // multiple of 4, min 4
        if (m == 0) m = 4;
        for (int i = cnt; i < m; ++i) dst[i] = (unsigned short)NPP; // zero row
        sCnt[row][rg] = m;
    }
    __syncthreads();

    const int oct = tid & 7;                // 16 B sub-chunk of 128 B row
    const int r   = tid >> 3;               // 0..31: this thread's row

    float a0 = 0.f, a1 = 0.f, a2 = 0.f, a3 = 0.f;
    float a4 = 0.f, a5 = 0.f, a6 = 0.f, a7 = 0.f;

#define ACC8(v)                                 \
    do {                                        \
        a0 += __uint_as_float((v).x << 16);     \
        a1 += __uint_as_float((v).x & 0xffff0000u); \
        a2 += __uint_as_float((v).y << 16);     \
        a3 += __uint_as_float((v).y & 0xffff0000u); \
        a4 += __uint_as_float((v).z << 16);     \
        a5 += __uint_as_float((v).z & 0xffff0000u); \
        a6 += __uint_as_float((v).w << 16);     \
        a7 += __uint_as_float((v).w & 0xffff0000u); \
    } while (0)

    for (int p = 0; p < 4; ++p) {           // temporal phases, same order
        const uintx4* __restrict__ Gc =
            (const uintx4*)G + (size_t)(p * 2 + h) * NPP1 * 8 + oct;
        const unsigned short* lp = &sC[r][p][0];
        const int m = sCnt[r][p];

        // two-stage pipeline: load batch i+4 while accumulating batch i
        uintx4 v0 = Gc[(size_t)lp[0] * 8];
        uintx4 v1 = Gc[(size_t)lp[1] * 8];
        uintx4 v2 = Gc[(size_t)lp[2] * 8];
        uintx4 v3 = Gc[(size_t)lp[3] * 8];
        for (int i = 4; i < m; i += 4) {
            const uintx4 w0 = Gc[(size_t)lp[i + 0] * 8];
            const uintx4 w1 = Gc[(size_t)lp[i + 1] * 8];
            const uintx4 w2 = Gc[(size_t)lp[i + 2] * 8];
            const uintx4 w3 = Gc[(size_t)lp[i + 3] * 8];
            ACC8(v0); ACC8(v1); ACC8(v2); ACC8(v3);
            v0 = w0; v1 = w1; v2 = w2; v3 = w3;
        }
        ACC8(v0); ACC8(v1); ACC8(v2); ACC8(v3);
    }
#undef ACC8

    const float inv = 1.0f / 25.0f;
    // 8 octs x 32 B = 256 B contiguous per row-half
    floatx4* op = (floatx4*)(out + (size_t)(row0 + r) * DIM + h * 64 + oct * 8);
    const floatx4 o0 = {fmaxf(a0 * inv, 0.f), fmaxf(a1 * inv, 0.f),
                        fmaxf(a2 * inv, 0.f), fmaxf(a3 * inv, 0.f)};
    const floatx4 o1 = {fmaxf(a4 * inv, 0.f), fmaxf(a5 * inv, 0.f),
                        fmaxf(a6 * inv, 0.f), fmaxf(a7 * inv, 0.f)};
    __builtin_nontemporal_store(o0, op);
    __builtin_nontemporal_store(o1, op + 1);
}

// --------------------------------------------- fallback (round-2 kernel) ----
#define RPB 16
#define CG 32

__device__ __forceinline__ float4 relu4(float4 v) {
    return make_float4(fmaxf(v.x, 0.f), fmaxf(v.y, 0.f),
                       fmaxf(v.z, 0.f), fmaxf(v.w, 0.f));
}

__global__ __launch_bounds__(256, 4) void gcn_fused(
    const float* __restrict__ F, const int* __restrict__ idx,
    const float* __restrict__ W, float* __restrict__ out, int n_rows)
{
    __shared__ float4 sV[RPB * CG];
    __shared__ int    sIdx[RPB * DEG];

    const float4* F4 = (const float4*)F;
    const float4* W4 = (const float4*)W;
    float4* out4 = (float4*)out;

    const int tid = threadIdx.x;
    const int row0 = blockIdx.x * RPB;

    for (int i = tid; i < RPB * DEG; i += 256)
        sIdx[i] = idx[(size_t)row0 * DEG + i];
    __syncthreads();

    const int cg = tid & 31;
    const int rs = tid >> 5;

#pragma unroll
    for (int rr = 0; rr < 2; ++rr) {
        const int r = rs + rr * 8;
        int j[DEG];
#pragma unroll
        for (int s = 0; s < DEG; ++s) j[s] = sIdx[r * DEG + s];
        float4 acc = make_float4(0.f, 0.f, 0.f, 0.f);
#pragma unroll
        for (int s = 0; s < DEG; ++s) {
            float4 f = F4[(size_t)j[s] * CG + cg];
            acc.x += f.x; acc.y += f.y; acc.z += f.z; acc.w += f.w;
        }
        const float inv = 1.0f / 25.0f;
        acc.x *= inv; acc.y *= inv; acc.z *= inv; acc.w *= inv;
        sV[r * CG + cg] = acc;
    }
    __syncthreads();

    const float4* vA = &sV[rs * CG];
    const float4* vB = &sV[(rs + 8) * CG];
    float4 o0 = make_float4(0.f, 0.f, 0.f, 0.f);
    float4 o1 = make_float4(0.f, 0.f, 0.f, 0.f);
#pragma unroll 4
    for (int d4 = 0; d4 < CG; ++d4) {
        const float4 a = vA[d4];
        const float4 b = vB[d4];
        const float4 w0 = W4[(size_t)(4 * d4 + 0) * CG + cg];
        const float4 w1 = W4[(size_t)(4 * d4 + 1) * CG + cg];
        const float4 w2 = W4[(size_t)(4 * d4 + 2) * CG + cg];
        const float4 w3 = W4[(size_t)(4 * d4 + 3) * CG + cg];
        o0.x += a.x*w0.x + a.y*w1.x + a.z*w2.x + a.w*w3.x;
        o0.y += a.x*w0.y + a.y*w1.y + a.z*w2.y + a.w*w3.y;
        o0.z += a.x*w0.z + a.y*w1.z + a.z*w2.z + a.w*w3.z;
        o0.w += a.x*w0.w + a.y*w1.w + a.z*w2.w + a.w*w3.w;
        o1.x += b.x*w0.x + b.y*w1.x + b.z*w2.x + b.w*w3.x;
        o1.y += b.x*w0.y + b.y*w1.y + b.z*w2.y + b.w*w3.y;
        o1.z += b.x*w0.z + b.y*w1.z + b.z*w2.z + b.w*w3.z;
        o1.w += b.x*w0.w + b.y*w1.w + b.z*w2.w + b.w*w3.w;
    }
    out4[(size_t)(row0 + rs) * CG + cg]     = relu4(o0);
    out4[(size_t)(row0 + rs + 8) * CG + cg] = relu4(o1);
}

// ----------------------------------------------------------------------------
extern "C" void kernel_launch(void* const* d_in, const int* in_sizes, int n_in,
                              void* d_out, int out_size, void* d_ws, size_t ws_size,
                              hipStream_t stream) {
    const float* F   = (const float*)d_in[0];   // features [100000,128] fp32
    const int*   idx = (const int*)d_in[1];     // sample_res [8,4096,25] int32
    const float* W   = (const float*)d_in[2];   // weights [128,128] fp32
    float* out = (float*)d_out;                 // [8,4096,128] fp32

    const int n_nodes = in_sizes[0] / DIM;      // 100000
    const int n_rows  = in_sizes[1] / DEG;      // 32768

    const size_t need = (size_t)8 * NPP1 * 64 * sizeof(unsigned short);

    if (n_nodes == 100000 && ws_size >= need && (n_rows & (GRB - 1)) == 0) {
        unsigned short* G = (unsigned short*)d_ws;
        gemm_fw<<<(n_nodes + 127) / 128, 256, 0, stream>>>(F, W, G, n_nodes);
        gather_phased<<<(n_rows / GRB) * 2, 256, 0, stream>>>(G, idx, out, n_rows);
    } else {
        gcn_fused<<<n_rows / RPB, 256, 0, stream>>>(F, idx, W, out, n_rows);
    }
}